// Round 1
// baseline (125.515 us; speedup 1.0000x reference)
//
#include <hip/hip_runtime.h>
#include <math.h>

// Problem constants (setup_inputs: T=16384, J=64, d=1024, all fp32)
#define T_DIM 16384
#define J_DIM 64
#define D_DIM 1024

// ws layout (float offsets)
#define E_OFF    0                 // m[t] then e[t] in-place, T floats
#define BMAX_OFF 16384             // 64 block maxes
#define BSUM_OFF 16448             // 64 block sums of e
#define INVZ_OFF 16512             // 1 float
#define CTX_OFF  16640             // 1024 floats (unnormalized ctx)
#define PART_OFF 17664             // 512*1024 partials (16B-aligned: 17664*4 % 16 == 0)

#define CTX_BLOCKS   512           // k3 grid: 2 blocks/CU
#define ROWS_PER_BLK 32            // T / CTX_BLOCKS

// K1: per-row max over J, per-block (256-row) max, zero ctx accumulator.
__global__ __launch_bounds__(256) void k1_rowmax(const float* __restrict__ s,
                                                 float* __restrict__ ws) {
    __shared__ float red[256];
    const int tid = threadIdx.x;
    const int t = blockIdx.x * 256 + tid;
    const float4* s4 = (const float4*)s + (size_t)t * (J_DIM / 4);
    float m = -INFINITY;
#pragma unroll
    for (int j = 0; j < J_DIM / 4; ++j) {
        float4 v = s4[j];
        m = fmaxf(m, fmaxf(fmaxf(v.x, v.y), fmaxf(v.z, v.w)));
    }
    ws[E_OFF + t] = m;
    red[tid] = m;
    __syncthreads();
    for (int off = 128; off > 0; off >>= 1) {
        if (tid < off) red[tid] = fmaxf(red[tid], red[tid + off]);
        __syncthreads();
    }
    if (tid == 0) ws[BMAX_OFF + blockIdx.x] = red[0];
    // zero the ctx accumulator (ws is poisoned 0xAA before every launch)
    if (blockIdx.x < D_DIM / 256) ws[CTX_OFF + blockIdx.x * 256 + tid] = 0.0f;
}

// K2: global max (each block redundantly reduces the 64 block maxes),
//     e[t] = exp(m[t]-M) in-place, per-block sum -> bsum[blockIdx].
__global__ __launch_bounds__(256) void k2_exp(float* __restrict__ ws) {
    __shared__ float red[256];
    const int tid = threadIdx.x;
    red[tid] = (tid < 64) ? ws[BMAX_OFF + tid] : -INFINITY;
    __syncthreads();
    for (int off = 128; off > 0; off >>= 1) {
        if (tid < off) red[tid] = fmaxf(red[tid], red[tid + off]);
        __syncthreads();
    }
    const float M = red[0];
    __syncthreads();
    const int t = blockIdx.x * 256 + tid;
    const float e = expf(ws[E_OFF + t] - M);
    ws[E_OFF + t] = e;
    red[tid] = e;
    __syncthreads();
    for (int off = 128; off > 0; off >>= 1) {
        if (tid < off) red[tid] += red[tid + off];
        __syncthreads();
    }
    if (tid == 0) ws[BSUM_OFF + blockIdx.x] = red[0];
}

// K3: the heavy pass. Block b covers rows [b*32, b*32+32); its 256 threads
// cover one full h row (1024 floats) per iteration as coalesced float4s.
// Weights (e[t]) staged in LDS. Writes per-block partial ctx (unnormalized).
__global__ __launch_bounds__(256) void k3_partial(const float* __restrict__ h,
                                                  float* __restrict__ ws) {
    __shared__ float w[ROWS_PER_BLK];
    const int tid = threadIdx.x;
    const int b = blockIdx.x;
    if (tid < ROWS_PER_BLK) w[tid] = ws[E_OFF + b * ROWS_PER_BLK + tid];
    __syncthreads();
    const float4* h4 = (const float4*)h;
    float4 acc = make_float4(0.f, 0.f, 0.f, 0.f);
    const size_t base = (size_t)b * ROWS_PER_BLK * (D_DIM / 4) + tid;
#pragma unroll 8
    for (int r = 0; r < ROWS_PER_BLK; ++r) {
        const float4 v = h4[base + (size_t)r * (D_DIM / 4)];
        const float wt = w[r];
        acc.x = fmaf(wt, v.x, acc.x);
        acc.y = fmaf(wt, v.y, acc.y);
        acc.z = fmaf(wt, v.z, acc.z);
        acc.w = fmaf(wt, v.w, acc.w);
    }
    ((float4*)(ws + PART_OFF))[(size_t)b * (D_DIM / 4) + tid] = acc;
}

// K4: reduce 512 partials -> ctx via 16-deep chunks + atomicAdd (16 atomics
// per address — negligible). Block 0 also computes invZ from the 64 bsums.
__global__ __launch_bounds__(256) void k4_reduce(float* __restrict__ ws) {
    __shared__ float red[64];
    const int tid = threadIdx.x;
    if (blockIdx.x == 0) {
        if (tid < 64) red[tid] = ws[BSUM_OFF + tid];
        __syncthreads();
        for (int off = 32; off > 0; off >>= 1) {
            if (tid < off) red[tid] += red[tid + off];
            __syncthreads();
        }
        if (tid == 0) ws[INVZ_OFF] = 1.0f / red[0];
    }
    const int pc = blockIdx.x >> 2;                    // 16 p-chunks of 32
    const int dd = (blockIdx.x & 3) * 256 + tid;       // 4 dd-chunks of 256
    const float* part = ws + PART_OFF;
    float sum = 0.f;
#pragma unroll 8
    for (int p = pc * 32; p < pc * 32 + 32; ++p) sum += part[(size_t)p * D_DIM + dd];
    atomicAdd(&ws[CTX_OFF + dd], sum);
}

// K5: broadcast write. out[dd*T + t] = ctx[dd] * invZ. Each block owns 1024
// consecutive float4s of one output row -> dd is block-uniform.
__global__ __launch_bounds__(256) void k5_broadcast(const float* __restrict__ ws,
                                                    float4* __restrict__ out4) {
    const int dd = blockIdx.x >> 4;                    // T/4/256 = 16 blocks per row
    const float v = ws[CTX_OFF + dd] * ws[INVZ_OFF];
    const size_t idx = (size_t)blockIdx.x * 256 + threadIdx.x;
    out4[idx] = make_float4(v, v, v, v);
}

extern "C" void kernel_launch(void* const* d_in, const int* in_sizes, int n_in,
                              void* d_out, int out_size, void* d_ws, size_t ws_size,
                              hipStream_t stream) {
    const float* h = (const float*)d_in[0];   // (1, T, d) fp32
    const float* s = (const float*)d_in[1];   // (T, J) fp32
    float* ws = (float*)d_ws;
    float4* out = (float4*)d_out;             // (d, T) fp32

    k1_rowmax<<<T_DIM / 256, 256, 0, stream>>>(s, ws);
    k2_exp<<<T_DIM / 256, 256, 0, stream>>>(ws);
    k3_partial<<<CTX_BLOCKS, 256, 0, stream>>>(h, ws);
    k4_reduce<<<64, 256, 0, stream>>>(ws);
    k5_broadcast<<<((size_t)D_DIM * T_DIM / 4) / 256, 256, 0, stream>>>(ws, out);
}

// Round 2
// 117.923 us; speedup vs baseline: 1.0644x; 1.0644x over previous
//
#include <hip/hip_runtime.h>
#include <math.h>

// Problem constants (setup_inputs: T=16384, J=64, d=1024, all fp32)
#define T_DIM 16384
#define J_DIM 64
#define D_DIM 1024

#define NB   512                  // heavy-pass blocks (2 per CU)
#define RPB  32                   // rows of h per block (T / NB)

// ws layout (float offsets). No zero-init required anywhere (no atomics).
#define MB_OFF   0                // 512 block maxes
#define ZB_OFF   512              // 512 block partial softmax denoms
#define PART_OFF 1024             // part[b][dd]: 512 x 1024 floats, 16B aligned

// ============================================================================
// kB: fused softmax-weights + heavy weighted-sum pass.
// Block b owns rows [b*32, b*32+32).
//   1) read its 32 s-rows (8 KB, coalesced float4), row-max via 16-lane
//      shuffle butterflies,
//   2) thread 0: block max Mb, weights w[r]=exp(m[r]-Mb), Zb=sum w  (tiny),
//   3) heavy pass: 256 threads sweep one 4 KB h-row per iteration as
//      coalesced float4 loads, FMA into per-thread float4 acc,
//   4) write partial ctx (coalesced float4) + Mb, Zb.
// ============================================================================
__global__ __launch_bounds__(256) void kb_heavy(const float* __restrict__ h,
                                                const float* __restrict__ s,
                                                float* __restrict__ ws) {
    __shared__ float rowmax[RPB];
    __shared__ float wts[RPB];
    const int tid = threadIdx.x;
    const int b = blockIdx.x;

    // --- 1) row maxes over J=64 (16 float4 per row; 16 consecutive lanes/row)
    const float4* s4 = (const float4*)s + (size_t)b * (RPB * J_DIM / 4); // 512 f4/block
    float4 v0 = s4[tid];
    float4 v1 = s4[tid + 256];
    float m0 = fmaxf(fmaxf(v0.x, v0.y), fmaxf(v0.z, v0.w));
    float m1 = fmaxf(fmaxf(v1.x, v1.y), fmaxf(v1.z, v1.w));
#pragma unroll
    for (int off = 1; off < 16; off <<= 1) {
        m0 = fmaxf(m0, __shfl_xor(m0, off));
        m1 = fmaxf(m1, __shfl_xor(m1, off));
    }
    if ((tid & 15) == 0) {
        rowmax[tid >> 4] = m0;            // rows 0..15
        rowmax[16 + (tid >> 4)] = m1;     // rows 16..31
    }
    __syncthreads();

    // --- 2) block max, local weights, local denom (serial: 32 iters, off BW path)
    if (tid == 0) {
        float Mb = rowmax[0];
#pragma unroll
        for (int r = 1; r < RPB; ++r) Mb = fmaxf(Mb, rowmax[r]);
        float Zb = 0.f;
#pragma unroll
        for (int r = 0; r < RPB; ++r) {
            const float w = expf(rowmax[r] - Mb);
            wts[r] = w;
            Zb += w;
        }
        ws[MB_OFF + b] = Mb;
        ws[ZB_OFF + b] = Zb;
    }
    __syncthreads();

    // --- 3) heavy pass: 32 rows x 1024 floats, perfectly coalesced
    const float4* h4 = (const float4*)h;
    float4 acc = make_float4(0.f, 0.f, 0.f, 0.f);
    const size_t base = (size_t)b * (RPB * D_DIM / 4) + tid;
#pragma unroll 8
    for (int r = 0; r < RPB; ++r) {
        const float4 v = h4[base + (size_t)r * (D_DIM / 4)];
        const float wt = wts[r];
        acc.x = fmaf(wt, v.x, acc.x);
        acc.y = fmaf(wt, v.y, acc.y);
        acc.z = fmaf(wt, v.z, acc.z);
        acc.w = fmaf(wt, v.w, acc.w);
    }

    // --- 4) partial ctx, coalesced float4 store: part[b][4tid..4tid+3]
    ((float4*)(ws + PART_OFF))[(size_t)b * (D_DIM / 4) + tid] = acc;
}

// ============================================================================
// kCD: fused rescale-reduce + broadcast. One block per output dim dd.
//   M = max_b Mb (LDS reduce), sc_b = exp(Mb-M),
//   Z = sum sc_b*Zb, ctx = sum sc_b*part[b][dd]   (part reads strided but
//   L2-resident: 2 MB x 16-way line reuse), then stream the 64 KB output
//   row out[dd][0..T) = ctx/Z as float4 stores.
// ============================================================================
__global__ __launch_bounds__(256) void kcd_reduce_bcast(const float* __restrict__ ws,
                                                        float4* __restrict__ out4) {
    __shared__ float redm[256];
    __shared__ float redz[256];
    __shared__ float redc[256];
    const int tid = threadIdx.x;
    const int dd = blockIdx.x;

    const float m0 = ws[MB_OFF + tid];
    const float m1 = ws[MB_OFF + tid + 256];
    // issue part loads early (independent of the max reduction)
    const float* prow = ws + PART_OFF + (size_t)tid * D_DIM + dd;
    const float p0 = prow[0];
    const float p1 = prow[(size_t)256 * D_DIM];
    const float z0 = ws[ZB_OFF + tid];
    const float z1 = ws[ZB_OFF + tid + 256];

    redm[tid] = fmaxf(m0, m1);
    __syncthreads();
#pragma unroll
    for (int off = 128; off > 0; off >>= 1) {
        if (tid < off) redm[tid] = fmaxf(redm[tid], redm[tid + off]);
        __syncthreads();
    }
    const float M = redm[0];

    const float s0 = expf(m0 - M);
    const float s1 = expf(m1 - M);
    redz[tid] = s0 * z0 + s1 * z1;
    redc[tid] = s0 * p0 + s1 * p1;
    __syncthreads();
#pragma unroll
    for (int off = 128; off > 0; off >>= 1) {
        if (tid < off) {
            redz[tid] += redz[tid + off];
            redc[tid] += redc[tid + off];
        }
        __syncthreads();
    }
    const float val = redc[0] / redz[0];

    const float4 v4 = make_float4(val, val, val, val);
    float4* o = out4 + (size_t)dd * (T_DIM / 4);
#pragma unroll
    for (int i = 0; i < T_DIM / 4 / 256; ++i)   // 16 float4 stores per thread
        o[(size_t)i * 256 + tid] = v4;
}

extern "C" void kernel_launch(void* const* d_in, const int* in_sizes, int n_in,
                              void* d_out, int out_size, void* d_ws, size_t ws_size,
                              hipStream_t stream) {
    const float* h = (const float*)d_in[0];   // (1, T, d) fp32
    const float* s = (const float*)d_in[1];   // (T, J) fp32
    float* ws = (float*)d_ws;
    float4* out = (float4*)d_out;             // (d, T) fp32

    kb_heavy<<<NB, 256, 0, stream>>>(h, s, ws);
    kcd_reduce_bcast<<<D_DIM, 256, 0, stream>>>(ws, out);
}